// Round 1
// baseline (387.630 us; speedup 1.0000x reference)
//
#include <hip/hip_runtime.h>
#include <hip/hip_bf16.h>

namespace {

constexpr int kB  = 32;
constexpr int kN  = 1024;
constexpr int kD  = 2;
constexpr int kU  = 64;
constexpr int kF  = 66;   // D + U
constexpr int kFP = 80;   // padded feature dim (5 tiles of 16)
constexpr int kRK = 198;  // (D+U)*(S+1)

typedef __attribute__((ext_vector_type(4))) float f32x4;
typedef __attribute__((ext_vector_type(8))) short sv8;

__device__ __forceinline__ unsigned pack_bf2(float a, float b) {
  __hip_bfloat16 ha = __float2bfloat16(a);
  __hip_bfloat16 hb = __float2bfloat16(b);
  unsigned short ua = *reinterpret_cast<unsigned short*>(&ha);
  unsigned short ub = *reinterpret_cast<unsigned short*>(&hb);
  return (unsigned)ua | ((unsigned)ub << 16);
}

// ---------------------------------------------------------------------------
// K1: build x0^T bf16 (B, 80, 1024). Rows [0,2) = inputs (written to BOTH x0t
// and x0tc), rows [2,66) of x0t = h_prev, rows [66,80) = 0 in both.
// x0tc rows [2,66) are filled later by gates_ru (r*h).
// ---------------------------------------------------------------------------
__global__ __launch_bounds__(256) void build_x0t(
    const float* __restrict__ inputs, const float* __restrict__ h_prev,
    __hip_bfloat16* __restrict__ x0t, __hip_bfloat16* __restrict__ x0tc) {
  const int bx = blockIdx.x;
  const int b  = bx >> 4;          // /16
  const int n0 = (bx & 15) * 64;   // n tile of 64
  const int t  = threadIdx.x;

  __shared__ float hp[64][65];

  const float* hpg = h_prev + (size_t)b * kN * kU + (size_t)n0 * kU;
#pragma unroll
  for (int r = 0; r < 16; ++r) {
    int idx = t + (r << 8);        // 4096 floats
    hp[idx >> 6][idx & 63] = hpg[idx];
  }
  __syncthreads();

  {  // state rows: x0t[b][2+u][n0+nn]
    int u = t >> 2, g = t & 3;
    __hip_bfloat16* dst = x0t + ((size_t)b * kFP + 2 + u) * kN + n0 + g * 16;
#pragma unroll
    for (int k = 0; k < 16; ++k) dst[k] = __float2bfloat16(hp[g * 16 + k][u]);
  }

  if (t < 128) {  // input rows f=0,1 -> both buffers
    int d = t & 1, nn = t >> 1;
    float v = inputs[((size_t)b * kN + n0 + nn) * kD + d];
    __hip_bfloat16 bv = __float2bfloat16(v);
    x0t [((size_t)b * kFP + d) * kN + n0 + nn] = bv;
    x0tc[((size_t)b * kFP + d) * kN + n0 + nn] = bv;
  } else {        // zero pad rows 66..79 in both buffers
    int i2 = t - 128;
    __hip_bfloat16 z = __float2bfloat16(0.0f);
#pragma unroll
    for (int r = 0; r < 7; ++r) {
      int idx = i2 + r * 128;      // 0..895 = 14 rows x 64 n
      int row = 66 + (idx >> 6), nn = idx & 63;
      x0t [((size_t)b * kFP + row) * kN + n0 + nn] = z;
      x0tc[((size_t)b * kFP + row) * kN + n0 + nn] = z;
    }
  }
}

// ---------------------------------------------------------------------------
// K2/K4: graph-diffusion einsum via bf16 MFMA.
// Block = (b, 64-row i-tile); 4 waves = (s in {0,1}) x (i-half in {0,1}).
// Per wave: 32 i x 80 f output, f32 accum. Writes full xfeat rows
// (m=0 term = x0 itself, m=1+s terms = supports@x0).
// ---------------------------------------------------------------------------
__global__ __launch_bounds__(256) void einsum_diff(
    const float* __restrict__ sup, const __hip_bfloat16* __restrict__ x0t,
    float* __restrict__ xfeat) {
  const int bx  = blockIdx.x;
  const int b   = bx >> 4;
  const int i0  = (bx & 15) << 6;
  const int t   = threadIdx.x;
  const int lane = t & 63;
  const int w   = t >> 6;
  const int q   = lane >> 4;
  const int lm  = lane & 15;
  const int s   = w & 1;
  const int ih  = w >> 1;

  __shared__ unsigned short Alds[2][64][72];  // [s][i][j] bf16, padded
  __shared__ unsigned short Xlds[80][72];     // [f][j] bf16, padded

  f32x4 acc[2][5];
#pragma unroll
  for (int m = 0; m < 2; ++m)
#pragma unroll
    for (int n = 0; n < 5; ++n) acc[m][n] = (f32x4){0.f, 0.f, 0.f, 0.f};

  const float* sbase = sup + ((size_t)b * kN + i0) * kN * 2;
  const unsigned* xbase =
      reinterpret_cast<const unsigned*>(x0t + (size_t)b * kFP * kN);

  for (int j0 = 0; j0 < kN; j0 += 64) {
    // ---- stage A tile (both supports), f32 -> bf16 ----
#pragma unroll
    for (int r = 0; r < 8; ++r) {
      int idx = t + (r << 8);      // 2048 float4 units
      int ii = idx >> 5, c = idx & 31;
      float4 v = *reinterpret_cast<const float4*>(
          sbase + (size_t)ii * (kN * 2) + j0 * 2 + c * 4);
      // v = {j=2c,s0},{2c,s1},{2c+1,s0},{2c+1,s1}
      *reinterpret_cast<unsigned*>(&Alds[0][ii][c * 2]) = pack_bf2(v.x, v.z);
      *reinterpret_cast<unsigned*>(&Alds[1][ii][c * 2]) = pack_bf2(v.y, v.w);
    }
    // ---- stage X^T tile (already bf16) ----
#pragma unroll
    for (int r = 0; r < 10; ++r) {
      int idx = t + (r << 8);      // 2560 u32 units
      int f = idx >> 5, c = idx & 31;
      unsigned v = xbase[(size_t)f * (kN / 2) + (j0 >> 1) + c];
      *reinterpret_cast<unsigned*>(&Xlds[f][c * 2]) = v;
    }
    __syncthreads();
    // ---- MFMA over this K-tile (K=64 = 2 x 32) ----
#pragma unroll
    for (int ks = 0; ks < 2; ++ks) {
      const int ko = ks * 32 + q * 8;
      sv8 a0 = *reinterpret_cast<const sv8*>(&Alds[s][ih * 32 + lm][ko]);
      sv8 a1 = *reinterpret_cast<const sv8*>(&Alds[s][ih * 32 + 16 + lm][ko]);
      sv8 bfr[5];
#pragma unroll
      for (int n = 0; n < 5; ++n)
        bfr[n] = *reinterpret_cast<const sv8*>(&Xlds[n * 16 + lm][ko]);
#pragma unroll
      for (int n = 0; n < 5; ++n) {
        acc[0][n] = __builtin_amdgcn_mfma_f32_16x16x32_bf16(a0, bfr[n], acc[0][n], 0, 0, 0);
        acc[1][n] = __builtin_amdgcn_mfma_f32_16x16x32_bf16(a1, bfr[n], acc[1][n], 0, 0, 0);
      }
    }
    __syncthreads();
  }

  // ---- epilogue: xm terms ----
  const size_t orow = (size_t)(b * kN) * kRK;
#pragma unroll
  for (int m = 0; m < 2; ++m) {
#pragma unroll
    for (int n = 0; n < 5; ++n) {
      int f = n * 16 + lm;
      if (f < kF) {
#pragma unroll
        for (int r = 0; r < 4; ++r) {
          int i = i0 + ih * 32 + m * 16 + q * 4 + r;
          xfeat[orow + (size_t)i * kRK + f * 3 + 1 + s] = acc[m][n][r];
        }
      }
    }
  }
  // ---- m=0 terms (x0 itself) ----
  for (int r0 = 0; r0 < 17; ++r0) {
    int idx = t + (r0 << 8);
    if (idx < 64 * kF) {
      int il = idx / kF, f = idx - il * kF;
      float v = __bfloat162float(x0t[((size_t)b * kFP + f) * kN + i0 + il]);
      xfeat[orow + (size_t)(i0 + il) * kRK + f * 3] = v;
    }
  }
}

// ---------------------------------------------------------------------------
// K3: r/u gates. 32 xfeat rows per block; r=sigmoid(xfeat@rk+rb),
// u=sigmoid(xfeat@uk+ub). Stores u and writes bf16(r*h_prev) into x0tc state.
// ---------------------------------------------------------------------------
__global__ __launch_bounds__(256) void gates_ru(
    const float* __restrict__ xfeat, const float* __restrict__ rk,
    const float* __restrict__ rb, const float* __restrict__ uk,
    const float* __restrict__ ub, const float* __restrict__ h_prev,
    float* __restrict__ u_buf, __hip_bfloat16* __restrict__ x0tc) {
  const int row0 = blockIdx.x * 32;
  const int t = threadIdx.x;
  __shared__ float xf[32][200];
  for (int r = 0; r < 25; ++r) {
    int idx = t + (r << 8);
    if (idx < 32 * kRK) {
      int rw = idx / kRK, k = idx - rw * kRK;
      xf[rw][k] = xfeat[(size_t)(row0 + rw) * kRK + k];
    }
  }
  __syncthreads();
  const int cu = t & 15;
  const int rw = t >> 4;
  float ar[2][4] = {{0.f,0.f,0.f,0.f},{0.f,0.f,0.f,0.f}};
  float au[2][4] = {{0.f,0.f,0.f,0.f},{0.f,0.f,0.f,0.f}};
  const float* xr0 = xf[rw * 2];
  const float* xr1 = xf[rw * 2 + 1];
#pragma unroll 2
  for (int k = 0; k < kRK; ++k) {
    float a0 = xr0[k], a1 = xr1[k];
    float4 vr = *reinterpret_cast<const float4*>(rk + k * kU + cu * 4);
    float4 vu = *reinterpret_cast<const float4*>(uk + k * kU + cu * 4);
    ar[0][0] += a0 * vr.x; ar[0][1] += a0 * vr.y; ar[0][2] += a0 * vr.z; ar[0][3] += a0 * vr.w;
    ar[1][0] += a1 * vr.x; ar[1][1] += a1 * vr.y; ar[1][2] += a1 * vr.z; ar[1][3] += a1 * vr.w;
    au[0][0] += a0 * vu.x; au[0][1] += a0 * vu.y; au[0][2] += a0 * vu.z; au[0][3] += a0 * vu.w;
    au[1][0] += a1 * vu.x; au[1][1] += a1 * vu.y; au[1][2] += a1 * vu.z; au[1][3] += a1 * vu.w;
  }
#pragma unroll
  for (int rr = 0; rr < 2; ++rr) {
    int grow = row0 + rw * 2 + rr;
    int b = grow >> 10, n = grow & 1023;
#pragma unroll
    for (int j = 0; j < 4; ++j) {
      int u = cu * 4 + j;
      float rv = 1.f / (1.f + expf(-(ar[rr][j] + rb[u])));
      float uv = 1.f / (1.f + expf(-(au[rr][j] + ub[u])));
      u_buf[(size_t)grow * kU + u] = uv;
      float rh = rv * h_prev[(size_t)grow * kU + u];
      x0tc[((size_t)b * kFP + 2 + u) * kN + n] = __float2bfloat16(rh);
    }
  }
}

// ---------------------------------------------------------------------------
// K5: c gate + GRU update. c=tanh(xfeat_c@ck+cb); h = u*h_prev + (1-u)*c.
// ---------------------------------------------------------------------------
__global__ __launch_bounds__(256) void gate_c_final(
    const float* __restrict__ xfeat, const float* __restrict__ ck,
    const float* __restrict__ cb, const float* __restrict__ h_prev,
    const float* __restrict__ u_buf, float* __restrict__ out) {
  const int row0 = blockIdx.x * 32;
  const int t = threadIdx.x;
  __shared__ float xf[32][200];
  for (int r = 0; r < 25; ++r) {
    int idx = t + (r << 8);
    if (idx < 32 * kRK) {
      int rw = idx / kRK, k = idx - rw * kRK;
      xf[rw][k] = xfeat[(size_t)(row0 + rw) * kRK + k];
    }
  }
  __syncthreads();
  const int cu = t & 15;
  const int rw = t >> 4;
  float ac[2][4] = {{0.f,0.f,0.f,0.f},{0.f,0.f,0.f,0.f}};
  const float* xr0 = xf[rw * 2];
  const float* xr1 = xf[rw * 2 + 1];
#pragma unroll 2
  for (int k = 0; k < kRK; ++k) {
    float a0 = xr0[k], a1 = xr1[k];
    float4 vc = *reinterpret_cast<const float4*>(ck + k * kU + cu * 4);
    ac[0][0] += a0 * vc.x; ac[0][1] += a0 * vc.y; ac[0][2] += a0 * vc.z; ac[0][3] += a0 * vc.w;
    ac[1][0] += a1 * vc.x; ac[1][1] += a1 * vc.y; ac[1][2] += a1 * vc.z; ac[1][3] += a1 * vc.w;
  }
#pragma unroll
  for (int rr = 0; rr < 2; ++rr) {
    int grow = row0 + rw * 2 + rr;
#pragma unroll
    for (int j = 0; j < 4; ++j) {
      int u = cu * 4 + j;
      float cv = tanhf(ac[rr][j] + cb[u]);
      float uv = u_buf[(size_t)grow * kU + u];
      float hp = h_prev[(size_t)grow * kU + u];
      out[(size_t)grow * kU + u] = uv * hp + (1.f - uv) * cv;
    }
  }
}

}  // namespace

extern "C" void kernel_launch(void* const* d_in, const int* in_sizes, int n_in,
                              void* d_out, int out_size, void* d_ws, size_t ws_size,
                              hipStream_t stream) {
  const float* inputs = (const float*)d_in[0];
  const float* sup    = (const float*)d_in[1];
  const float* h_prev = (const float*)d_in[2];
  const float* rk     = (const float*)d_in[3];
  const float* rb     = (const float*)d_in[4];
  const float* uk     = (const float*)d_in[5];
  const float* ub     = (const float*)d_in[6];
  const float* ck     = (const float*)d_in[7];
  const float* cb     = (const float*)d_in[8];
  float* out = (float*)d_out;

  char* ws = (char*)d_ws;
  // workspace layout (total ~44.8 MB)
  __hip_bfloat16* x0t  = (__hip_bfloat16*)(ws);                     // 5,242,880 B
  __hip_bfloat16* x0tc = (__hip_bfloat16*)(ws + 5242880);           // 5,242,880 B
  float*          xfeat = (float*)(ws + 10485760);                  // 25,952,256 B
  float*          u_buf = (float*)(ws + 36438016);                  // 8,388,608 B

  hipLaunchKernelGGL(build_x0t, dim3(512), dim3(256), 0, stream,
                     inputs, h_prev, x0t, x0tc);
  hipLaunchKernelGGL(einsum_diff, dim3(512), dim3(256), 0, stream,
                     sup, x0t, xfeat);
  hipLaunchKernelGGL(gates_ru, dim3(1024), dim3(256), 0, stream,
                     xfeat, rk, rb, uk, ub, h_prev, u_buf, x0tc);
  hipLaunchKernelGGL(einsum_diff, dim3(512), dim3(256), 0, stream,
                     sup, x0tc, xfeat);
  hipLaunchKernelGGL(gate_c_final, dim3(1024), dim3(256), 0, stream,
                     xfeat, ck, cb, h_prev, u_buf, out);
}

// Round 2
// 331.508 us; speedup vs baseline: 1.1693x; 1.1693x over previous
//
#include <hip/hip_runtime.h>
#include <hip/hip_bf16.h>

namespace {

constexpr int kN  = 1024;
constexpr int kU  = 64;
constexpr int kFP = 80;   // padded feature dim (5 tiles of 16)
constexpr int kXR = 132;  // xfeat row = 2 supports * 66 features (m-major, m0 dropped)

typedef __attribute__((ext_vector_type(4))) float f32x4;
typedef __attribute__((ext_vector_type(8))) short sv8;

__device__ __forceinline__ unsigned pack_bf2(float a, float b) {
  __hip_bfloat16 ha = __float2bfloat16(a);
  __hip_bfloat16 hb = __float2bfloat16(b);
  unsigned short ua = *reinterpret_cast<unsigned short*>(&ha);
  unsigned short ub = *reinterpret_cast<unsigned short*>(&hb);
  return (unsigned)ua | ((unsigned)ub << 16);
}

// ---------------------------------------------------------------------------
// K1: build x0^T bf16 (B, 80, 1024). Rows [0,2) = inputs (both buffers),
// rows [2,66) of x0t = h_prev, rows [66,80) = 0 in both.
// x0tc state rows filled later by gates_ru (r*h).
// ---------------------------------------------------------------------------
__global__ __launch_bounds__(256) void build_x0t(
    const float* __restrict__ inputs, const float* __restrict__ h_prev,
    __hip_bfloat16* __restrict__ x0t, __hip_bfloat16* __restrict__ x0tc) {
  const int bx = blockIdx.x;
  const int b  = bx >> 4;
  const int n0 = (bx & 15) * 64;
  const int t  = threadIdx.x;

  __shared__ float hp[64][65];

  const float* hpg = h_prev + (size_t)b * kN * kU + (size_t)n0 * kU;
#pragma unroll
  for (int r = 0; r < 16; ++r) {
    int idx = t + (r << 8);
    hp[idx >> 6][idx & 63] = hpg[idx];
  }
  __syncthreads();

  {  // state rows: x0t[b][2+u][n0+nn]
    int u = t >> 2, g = t & 3;
    __hip_bfloat16* dst = x0t + ((size_t)b * kFP + 2 + u) * kN + n0 + g * 16;
#pragma unroll
    for (int k = 0; k < 16; ++k) dst[k] = __float2bfloat16(hp[g * 16 + k][u]);
  }

  if (t < 128) {  // input rows f=0,1 -> both buffers
    int d = t & 1, nn = t >> 1;
    float v = inputs[((size_t)b * kN + n0 + nn) * 2 + d];
    __hip_bfloat16 bv = __float2bfloat16(v);
    x0t [((size_t)b * kFP + d) * kN + n0 + nn] = bv;
    x0tc[((size_t)b * kFP + d) * kN + n0 + nn] = bv;
  } else {        // zero pad rows 66..79 in both buffers
    int i2 = t - 128;
    __hip_bfloat16 z = __float2bfloat16(0.0f);
#pragma unroll
    for (int r = 0; r < 7; ++r) {
      int idx = i2 + r * 128;
      int row = 66 + (idx >> 6), nn = idx & 63;
      x0t [((size_t)b * kFP + row) * kN + n0 + nn] = z;
      x0tc[((size_t)b * kFP + row) * kN + n0 + nn] = z;
    }
  }
}

// ---------------------------------------------------------------------------
// K2/K4: graph-diffusion einsum via bf16 MFMA, double-buffered reg-staging.
// Block = (b, 32-row i-tile), grid 1024 (4 blocks/CU). 4 waves = s x ih.
// Wave computes 16 i-rows x 80 f for its support s; f32 accum.
// LDS fragment-major: reads are base + lane*16 (conflict-free b128).
// xfeat layout: [b][i][s*66 + f] (m-major, m0 term omitted).
// ---------------------------------------------------------------------------
__global__ __launch_bounds__(256, 4) void einsum_diff(
    const float* __restrict__ sup, const __hip_bfloat16* __restrict__ x0t,
    float* __restrict__ xfeat) {
  const int bx   = blockIdx.x;
  const int b    = bx >> 5;
  const int i0   = (bx & 31) << 5;
  const int t    = threadIdx.x;
  const int lane = t & 63;
  const int w    = t >> 6;
  const int q    = lane >> 4;
  const int lm   = lane & 15;
  const int s    = w & 1;
  const int ih   = w >> 1;

  __shared__ unsigned short Xf[2][10][64][8];       // [buf][ks*5+n][lane][8]
  __shared__ unsigned short Af[2][2][2][2][64][8];  // [buf][s][ks][ih][lane][8]

  f32x4 acc[5];
#pragma unroll
  for (int n = 0; n < 5; ++n) acc[n] = (f32x4){0.f, 0.f, 0.f, 0.f};

  const float* sbase = sup + ((size_t)b * kN + i0) * (kN * 2);
  const unsigned short* xg =
      reinterpret_cast<const unsigned short*>(x0t) + (size_t)b * kFP * kN;

  // X staging per-unit global offsets (ushort units), constant across iters
  int xgo[3];
  bool xok[3];
#pragma unroll
  for (int uu = 0; uu < 3; ++uu) {
    int fl = t + (uu << 8);
    xok[uu] = fl < 640;
    int seg = fl >> 6, ln = fl & 63;
    int ff = (seg % 5) * 16 + (ln & 15);
    int jj = (seg / 5) * 32 + ((ln >> 4) & 3) * 8;
    xgo[uu] = ff * kN + jj;
  }

  float4 areg[4];
  uint4  xreg[3];

  auto loadRegs = [&](int j0) {
#pragma unroll
    for (int r = 0; r < 4; ++r) {
      int fl = t + (r << 8);
      int ii = fl >> 5, cc = fl & 31;
      areg[r] = *reinterpret_cast<const float4*>(
          sbase + (size_t)ii * (kN * 2) + j0 * 2 + cc * 4);
    }
#pragma unroll
    for (int uu = 0; uu < 3; ++uu)
      if (xok[uu])
        xreg[uu] = *reinterpret_cast<const uint4*>(xg + xgo[uu] + j0);
  };

  auto writeLds = [&](int nb) {
    uint4* xbuf = reinterpret_cast<uint4*>(&Xf[nb][0][0][0]);
#pragma unroll
    for (int uu = 0; uu < 3; ++uu)
      if (xok[uu]) xbuf[t + (uu << 8)] = xreg[uu];
#pragma unroll
    for (int r = 0; r < 4; ++r) {
      int fl = t + (r << 8);
      int ii = fl >> 5, cc = fl & 31;
      int ks = cc >> 4, cb2 = cc & 15;
      int q2 = cb2 >> 2, e = (cb2 & 3) * 2;  // j-pair within 8-elem group
      int lane2 = q2 * 16 + (ii & 15);
      int ihh = ii >> 4;
      float4 v = areg[r];
      *reinterpret_cast<unsigned*>(&Af[nb][0][ks][ihh][lane2][e]) = pack_bf2(v.x, v.z);
      *reinterpret_cast<unsigned*>(&Af[nb][1][ks][ihh][lane2][e]) = pack_bf2(v.y, v.w);
    }
  };

  auto compute = [&](int cb_) {
#pragma unroll
    for (int ks = 0; ks < 2; ++ks) {
      sv8 a = *reinterpret_cast<const sv8*>(&Af[cb_][s][ks][ih][lane][0]);
#pragma unroll
      for (int n = 0; n < 5; ++n) {
        sv8 xb = *reinterpret_cast<const sv8*>(&Xf[cb_][ks * 5 + n][lane][0]);
        acc[n] = __builtin_amdgcn_mfma_f32_16x16x32_bf16(a, xb, acc[n], 0, 0, 0);
      }
    }
  };

  loadRegs(0);
  writeLds(0);
  __syncthreads();

  for (int it = 0; it < 16; ++it) {
    int cur = it & 1;
    if (it < 15) loadRegs((it + 1) << 6);  // issue next-tile loads first
    compute(cur);
    if (it < 15) writeLds(cur ^ 1);        // land them after compute
    __syncthreads();
  }

  // epilogue: coalesced writes, 16 consecutive f per 16-lane group
  size_t rbase = ((size_t)(b * kN) + i0 + ih * 16 + q * 4) * kXR + s * 66;
#pragma unroll
  for (int n = 0; n < 5; ++n) {
    int f = n * 16 + lm;
    if (f < 66) {
#pragma unroll
      for (int r = 0; r < 4; ++r)
        xfeat[rbase + (size_t)r * kXR + f] = acc[n][r];
    }
  }
}

// ---------------------------------------------------------------------------
// K3: r/u gates. 32 rows per block. m0 term computed from inputs/h_prev
// directly; m=1,2 from xfeat. Writes u (f32) and bf16(r*h) into x0tc.
// ---------------------------------------------------------------------------
__global__ __launch_bounds__(256) void gates_ru(
    const float* __restrict__ xfeat, const float* __restrict__ rk,
    const float* __restrict__ rbias, const float* __restrict__ uk,
    const float* __restrict__ ubias, const float* __restrict__ inputs,
    const float* __restrict__ h_prev, float* __restrict__ u_buf,
    __hip_bfloat16* __restrict__ x0tc) {
  const int row0 = blockIdx.x * 32;
  const int b = row0 >> 10, n0 = row0 & 1023;
  const int t = threadIdx.x;
  __shared__ float xm[32][132];
  __shared__ float x0s[32][66];

  {
    const float4* xsrc = reinterpret_cast<const float4*>(xfeat + (size_t)row0 * kXR);
    float4* xdst = reinterpret_cast<float4*>(&xm[0][0]);
#pragma unroll
    for (int r2 = 0; r2 < 5; ++r2) {
      int fl = t + (r2 << 8);
      if (fl < 1056) xdst[fl] = xsrc[fl];
    }
  }
#pragma unroll
  for (int r2 = 0; r2 < 8; ++r2) {
    int idx = t + (r2 << 8);
    int rw = idx >> 6, u = idx & 63;
    x0s[rw][2 + u] = h_prev[(size_t)(row0 + rw) * kU + u];
  }
  if (t < 64) x0s[t >> 1][t & 1] = inputs[(size_t)row0 * 2 + t];
  __syncthreads();

  const int cu = t & 15;
  const int rw = (t >> 4) * 2;
  float ar[2][4] = {{0.f,0.f,0.f,0.f},{0.f,0.f,0.f,0.f}};
  float au[2][4] = {{0.f,0.f,0.f,0.f},{0.f,0.f,0.f,0.f}};

#pragma unroll 4
  for (int f = 0; f < 66; ++f) {  // m = 0
    float4 vr = *reinterpret_cast<const float4*>(rk + (size_t)(f * 3) * kU + cu * 4);
    float4 vu = *reinterpret_cast<const float4*>(uk + (size_t)(f * 3) * kU + cu * 4);
    float a0 = x0s[rw][f], a1 = x0s[rw + 1][f];
    ar[0][0] += a0 * vr.x; ar[0][1] += a0 * vr.y; ar[0][2] += a0 * vr.z; ar[0][3] += a0 * vr.w;
    ar[1][0] += a1 * vr.x; ar[1][1] += a1 * vr.y; ar[1][2] += a1 * vr.z; ar[1][3] += a1 * vr.w;
    au[0][0] += a0 * vu.x; au[0][1] += a0 * vu.y; au[0][2] += a0 * vu.z; au[0][3] += a0 * vu.w;
    au[1][0] += a1 * vu.x; au[1][1] += a1 * vu.y; au[1][2] += a1 * vu.z; au[1][3] += a1 * vu.w;
  }
#pragma unroll
  for (int m = 1; m <= 2; ++m) {
#pragma unroll 4
    for (int f = 0; f < 66; ++f) {
      float4 vr = *reinterpret_cast<const float4*>(rk + (size_t)(f * 3 + m) * kU + cu * 4);
      float4 vu = *reinterpret_cast<const float4*>(uk + (size_t)(f * 3 + m) * kU + cu * 4);
      float a0 = xm[rw][(m - 1) * 66 + f], a1 = xm[rw + 1][(m - 1) * 66 + f];
      ar[0][0] += a0 * vr.x; ar[0][1] += a0 * vr.y; ar[0][2] += a0 * vr.z; ar[0][3] += a0 * vr.w;
      ar[1][0] += a1 * vr.x; ar[1][1] += a1 * vr.y; ar[1][2] += a1 * vr.z; ar[1][3] += a1 * vr.w;
      au[0][0] += a0 * vu.x; au[0][1] += a0 * vu.y; au[0][2] += a0 * vu.z; au[0][3] += a0 * vu.w;
      au[1][0] += a1 * vu.x; au[1][1] += a1 * vu.y; au[1][2] += a1 * vu.z; au[1][3] += a1 * vu.w;
    }
  }

#pragma unroll
  for (int rr = 0; rr < 2; ++rr) {
    int grow = row0 + rw + rr;
    int n = n0 + rw + rr;
#pragma unroll
    for (int j = 0; j < 4; ++j) {
      int u = cu * 4 + j;
      float rv = 1.f / (1.f + __expf(-(ar[rr][j] + rbias[u])));
      float uv = 1.f / (1.f + __expf(-(au[rr][j] + ubias[u])));
      u_buf[(size_t)grow * kU + u] = uv;
      float rh = rv * h_prev[(size_t)grow * kU + u];
      x0tc[((size_t)b * kFP + 2 + u) * kN + n] = __float2bfloat16(rh);
    }
  }
}

// ---------------------------------------------------------------------------
// K5: c gate + GRU update. m0 state term from bf16 x0tc (r*h).
// ---------------------------------------------------------------------------
__global__ __launch_bounds__(256) void gate_c_final(
    const float* __restrict__ xfeat, const float* __restrict__ ck,
    const float* __restrict__ cbias, const float* __restrict__ inputs,
    const __hip_bfloat16* __restrict__ x0tc, const float* __restrict__ h_prev,
    const float* __restrict__ u_buf, float* __restrict__ out) {
  const int row0 = blockIdx.x * 32;
  const int b = row0 >> 10, n0 = row0 & 1023;
  const int t = threadIdx.x;
  __shared__ float xm[32][132];
  __shared__ float x0c[32][66];

  {
    const float4* xsrc = reinterpret_cast<const float4*>(xfeat + (size_t)row0 * kXR);
    float4* xdst = reinterpret_cast<float4*>(&xm[0][0]);
#pragma unroll
    for (int r2 = 0; r2 < 5; ++r2) {
      int fl = t + (r2 << 8);
      if (fl < 1056) xdst[fl] = xsrc[fl];
    }
  }
#pragma unroll
  for (int r2 = 0; r2 < 8; ++r2) {
    int idx = t + (r2 << 8);
    int u = idx >> 5, nn = idx & 31;
    x0c[nn][2 + u] =
        __bfloat162float(x0tc[((size_t)b * kFP + 2 + u) * kN + n0 + nn]);
  }
  if (t < 64) x0c[t >> 1][t & 1] = inputs[(size_t)row0 * 2 + t];
  __syncthreads();

  const int cu = t & 15;
  const int rw = (t >> 4) * 2;
  float ac[2][4] = {{0.f,0.f,0.f,0.f},{0.f,0.f,0.f,0.f}};

#pragma unroll 4
  for (int f = 0; f < 66; ++f) {  // m = 0
    float4 vc = *reinterpret_cast<const float4*>(ck + (size_t)(f * 3) * kU + cu * 4);
    float a0 = x0c[rw][f], a1 = x0c[rw + 1][f];
    ac[0][0] += a0 * vc.x; ac[0][1] += a0 * vc.y; ac[0][2] += a0 * vc.z; ac[0][3] += a0 * vc.w;
    ac[1][0] += a1 * vc.x; ac[1][1] += a1 * vc.y; ac[1][2] += a1 * vc.z; ac[1][3] += a1 * vc.w;
  }
#pragma unroll
  for (int m = 1; m <= 2; ++m) {
#pragma unroll 4
    for (int f = 0; f < 66; ++f) {
      float4 vc = *reinterpret_cast<const float4*>(ck + (size_t)(f * 3 + m) * kU + cu * 4);
      float a0 = xm[rw][(m - 1) * 66 + f], a1 = xm[rw + 1][(m - 1) * 66 + f];
      ac[0][0] += a0 * vc.x; ac[0][1] += a0 * vc.y; ac[0][2] += a0 * vc.z; ac[0][3] += a0 * vc.w;
      ac[1][0] += a1 * vc.x; ac[1][1] += a1 * vc.y; ac[1][2] += a1 * vc.z; ac[1][3] += a1 * vc.w;
    }
  }

#pragma unroll
  for (int rr = 0; rr < 2; ++rr) {
    int grow = row0 + rw + rr;
#pragma unroll
    for (int j = 0; j < 4; ++j) {
      int u = cu * 4 + j;
      float cv = tanhf(ac[rr][j] + cbias[u]);
      float uv = u_buf[(size_t)grow * kU + u];
      float hp = h_prev[(size_t)grow * kU + u];
      out[(size_t)grow * kU + u] = uv * hp + (1.f - uv) * cv;
    }
  }
}

}  // namespace

extern "C" void kernel_launch(void* const* d_in, const int* in_sizes, int n_in,
                              void* d_out, int out_size, void* d_ws, size_t ws_size,
                              hipStream_t stream) {
  const float* inputs = (const float*)d_in[0];
  const float* sup    = (const float*)d_in[1];
  const float* h_prev = (const float*)d_in[2];
  const float* rk     = (const float*)d_in[3];
  const float* rbias  = (const float*)d_in[4];
  const float* uk     = (const float*)d_in[5];
  const float* ubias  = (const float*)d_in[6];
  const float* ck     = (const float*)d_in[7];
  const float* cbias  = (const float*)d_in[8];
  float* out = (float*)d_out;

  char* ws = (char*)d_ws;
  // workspace layout (~36.2 MB)
  __hip_bfloat16* x0t   = (__hip_bfloat16*)(ws);                    //  5,242,880 B
  __hip_bfloat16* x0tc  = (__hip_bfloat16*)(ws + 5242880);          //  5,242,880 B
  float*          xfeat = (float*)(ws + 10485760);                  // 17,301,504 B
  float*          u_buf = (float*)(ws + 27787264);                  //  8,388,608 B

  hipLaunchKernelGGL(build_x0t, dim3(512), dim3(256), 0, stream,
                     inputs, h_prev, x0t, x0tc);
  hipLaunchKernelGGL(einsum_diff, dim3(1024), dim3(256), 0, stream,
                     sup, x0t, xfeat);
  hipLaunchKernelGGL(gates_ru, dim3(1024), dim3(256), 0, stream,
                     xfeat, rk, rbias, uk, ubias, inputs, h_prev, u_buf, x0tc);
  hipLaunchKernelGGL(einsum_diff, dim3(1024), dim3(256), 0, stream,
                     sup, x0tc, xfeat);
  hipLaunchKernelGGL(gate_c_final, dim3(1024), dim3(256), 0, stream,
                     xfeat, ck, cbias, inputs, x0tc, h_prev, u_buf, out);
}

// Round 3
// 253.616 us; speedup vs baseline: 1.5284x; 1.3071x over previous
//
#include <hip/hip_runtime.h>
#include <hip/hip_bf16.h>

namespace {

constexpr int kN  = 1024;
constexpr int kU  = 64;
constexpr int kFP = 80;   // padded feature dim (5 tiles of 16)
constexpr int kXR = 132;  // xfeat row = 2 supports * 66 features (m-major, m0 dropped)

typedef __attribute__((ext_vector_type(4))) float f32x4;
typedef __attribute__((ext_vector_type(8))) short sv8;
typedef unsigned int u32;

__device__ __forceinline__ unsigned pack_bf2(float a, float b) {
  __hip_bfloat16 ha = __float2bfloat16(a);
  __hip_bfloat16 hb = __float2bfloat16(b);
  unsigned short ua = *reinterpret_cast<unsigned short*>(&ha);
  unsigned short ub = *reinterpret_cast<unsigned short*>(&hb);
  return (unsigned)ua | ((unsigned)ub << 16);
}

__device__ __forceinline__ void gl16(const void* g, void* l) {
  __builtin_amdgcn_global_load_lds(
      (const __attribute__((address_space(1))) u32*)g,
      (__attribute__((address_space(3))) u32*)l, 16, 0, 0);
}

// ---------------------------------------------------------------------------
// K1: build x0^T bf16 (B, 80, 1024).
// ---------------------------------------------------------------------------
__global__ __launch_bounds__(256) void build_x0t(
    const float* __restrict__ inputs, const float* __restrict__ h_prev,
    __hip_bfloat16* __restrict__ x0t, __hip_bfloat16* __restrict__ x0tc) {
  const int bx = blockIdx.x;
  const int b  = bx >> 4;
  const int n0 = (bx & 15) * 64;
  const int t  = threadIdx.x;

  __shared__ float hp[64][65];

  const float* hpg = h_prev + (size_t)b * kN * kU + (size_t)n0 * kU;
#pragma unroll
  for (int r = 0; r < 16; ++r) {
    int idx = t + (r << 8);
    hp[idx >> 6][idx & 63] = hpg[idx];
  }
  __syncthreads();

  {
    int u = t >> 2, g = t & 3;
    __hip_bfloat16* dst = x0t + ((size_t)b * kFP + 2 + u) * kN + n0 + g * 16;
#pragma unroll
    for (int k = 0; k < 16; ++k) dst[k] = __float2bfloat16(hp[g * 16 + k][u]);
  }

  if (t < 128) {
    int d = t & 1, nn = t >> 1;
    float v = inputs[((size_t)b * kN + n0 + nn) * 2 + d];
    __hip_bfloat16 bv = __float2bfloat16(v);
    x0t [((size_t)b * kFP + d) * kN + n0 + nn] = bv;
    x0tc[((size_t)b * kFP + d) * kN + n0 + nn] = bv;
  } else {
    int i2 = t - 128;
    __hip_bfloat16 z = __float2bfloat16(0.0f);
#pragma unroll
    for (int r = 0; r < 7; ++r) {
      int idx = i2 + r * 128;
      int row = 66 + (idx >> 6), nn = idx & 63;
      x0t [((size_t)b * kFP + row) * kN + n0 + nn] = z;
      x0tc[((size_t)b * kFP + row) * kN + n0 + nn] = z;
    }
  }
}

// ---------------------------------------------------------------------------
// K2/K4: graph-diffusion einsum, bf16 MFMA, counted-vmcnt async pipeline.
// A (supports): depth-2 register prefetch -> bf16 repack -> LDS.
// X (x0t): global_load_lds DMA, depth-1, double-buffered.
// Raw s_barrier with manual lgkmcnt(0); vmcnt(4) mid-loop (never 0).
// ---------------------------------------------------------------------------
__global__ __launch_bounds__(256, 4) void einsum_diff(
    const float* __restrict__ sup, const __hip_bfloat16* __restrict__ x0t,
    float* __restrict__ xfeat) {
  const int bx   = blockIdx.x;
  const int b    = bx >> 5;
  const int i0   = (bx & 31) << 5;
  const int t    = threadIdx.x;
  const int lane = t & 63;
  const int w    = t >> 6;
  const int q    = lane >> 4;
  const int lm   = lane & 15;
  const int s    = w & 1;
  const int ih   = w >> 1;

  __shared__ unsigned short Xf[2][10][64][8];       // [buf][ks*5+n][lane][8]
  __shared__ unsigned short Af[2][2][2][2][64][8];  // [buf][s][ks][ih][lane][8]

  f32x4 acc[5];
#pragma unroll
  for (int n = 0; n < 5; ++n) acc[n] = (f32x4){0.f, 0.f, 0.f, 0.f};

  const float* sbase = sup + ((size_t)b * kN + i0) * (kN * 2);
  const unsigned short* xg =
      reinterpret_cast<const unsigned short*>(x0t) + (size_t)b * kFP * kN;

  // A-tile per-thread source bases (advance 128 floats per j-tile of 64)
  const float* aB[4];
#pragma unroll
  for (int r = 0; r < 4; ++r) {
    int fl = t + (r << 8);
    int ii = fl >> 5, cc = fl & 31;
    aB[r] = sbase + (size_t)ii * (kN * 2) + cc * 4;
  }

  // X DMA per-lane source bases for this wave's segments (seg = w, w+4, w+8)
  // seg -> (ks = seg/5, n = seg%5); lane (q,lm) reads 16B at
  // (n*16+lm)*kN + ks*32 + q*8 (ushort units), + 64 per j-tile.
  const unsigned short* xsA;
  const unsigned short* xsB;
  const unsigned short* xsC;
  {
    int segA = w;          // ks=0, n=w
    int segB = w + 4;
    int segC = w + 8;      // only valid for w<2
    int ksA = segA / 5, nA = segA % 5;
    int ksB = segB / 5, nB = segB % 5;
    int ksC = segC / 5, nC = segC % 5;
    xsA = xg + (size_t)(nA * 16 + lm) * kN + ksA * 32 + q * 8;
    xsB = xg + (size_t)(nB * 16 + lm) * kN + ksB * 32 + q * 8;
    xsC = xg + (size_t)(nC * 16 + lm) * kN + ksC * 32 + q * 8;
  }

  auto dmaX = [&](int nb, int T) {
    int jo = T * 64;
    gl16(xsA + jo, &Xf[nb][w][0][0]);
    gl16(xsB + jo, &Xf[nb][w + 4][0][0]);
    if (w < 2) gl16(xsC + jo, &Xf[nb][w + 8][0][0]);
  };

  auto loadA = [&](float4 (&R)[4], int T) {
    int jo2 = T * 128;  // floats
#pragma unroll
    for (int r = 0; r < 4; ++r)
      R[r] = *reinterpret_cast<const float4*>(aB[r] + jo2);
  };

  auto repack = [&](const float4 (&cur)[4], int nb) {
#pragma unroll
    for (int r = 0; r < 4; ++r) {
      int fl = t + (r << 8);
      int ii = fl >> 5, cc = fl & 31;
      int ks = cc >> 4, cb2 = cc & 15;
      int q2 = cb2 >> 2, e = (cb2 & 3) * 2;
      int lane2 = q2 * 16 + (ii & 15);
      int ihh = ii >> 4;
      float4 v = cur[r];
      *reinterpret_cast<u32*>(&Af[nb][0][ks][ihh][lane2][e]) = pack_bf2(v.x, v.z);
      *reinterpret_cast<u32*>(&Af[nb][1][ks][ihh][lane2][e]) = pack_bf2(v.y, v.w);
    }
  };

  auto compute = [&](int cb_) {
#pragma unroll
    for (int ks = 0; ks < 2; ++ks) {
      sv8 a = *reinterpret_cast<const sv8*>(&Af[cb_][s][ks][ih][lane][0]);
#pragma unroll
      for (int n = 0; n < 5; ++n) {
        sv8 xb = *reinterpret_cast<const sv8*>(&Xf[cb_][ks * 5 + n][lane][0]);
        acc[n] = __builtin_amdgcn_mfma_f32_16x16x32_bf16(a, xb, acc[n], 0, 0, 0);
      }
    }
  };

  float4 P[4], Q[4];

  // ---- prologue: tile 0 staged, A(1) in flight ----
  dmaX(0, 0);
  loadA(P, 0);
  asm volatile("s_waitcnt vmcnt(0)" ::: "memory");
  repack(P, 0);
  loadA(P, 1);
  asm volatile("s_waitcnt lgkmcnt(0)" ::: "memory");
  __builtin_amdgcn_s_barrier();
  __builtin_amdgcn_sched_barrier(0);

#define BODY(T, CUR, NXT, ISSUE)                                      \
  {                                                                   \
    const int nb_ = ((T) + 1) & 1;                                    \
    dmaX(nb_, (T) + 1);                                               \
    if (ISSUE) loadA(NXT, (T) + 2);                                   \
    compute((T) & 1);                                                 \
    if (ISSUE) { asm volatile("s_waitcnt vmcnt(4)" ::: "memory"); }   \
    else       { asm volatile("s_waitcnt vmcnt(0)" ::: "memory"); }   \
    repack(CUR, nb_);                                                 \
    asm volatile("s_waitcnt lgkmcnt(0)" ::: "memory");                \
    __builtin_amdgcn_s_barrier();                                     \
    __builtin_amdgcn_sched_barrier(0);                                \
  }

#pragma unroll 1
  for (int t2 = 0; t2 < 7; ++t2) {
    int tt = t2 * 2;
    BODY(tt,     P, Q, true);
    BODY(tt + 1, Q, P, true);
  }
  BODY(14, P, Q, false);
  compute(1);  // tile 15
#undef BODY

  // ---- epilogue: coalesced writes, 16 consecutive f per 16-lane group ----
  size_t rbase = ((size_t)(b * kN) + i0 + ih * 16 + q * 4) * kXR + s * 66;
#pragma unroll
  for (int n = 0; n < 5; ++n) {
    int f = n * 16 + lm;
    if (f < 66) {
#pragma unroll
      for (int r = 0; r < 4; ++r)
        xfeat[rbase + (size_t)r * kXR + f] = acc[n][r];
    }
  }
}

// ---------------------------------------------------------------------------
// K3: r/u gates.
// ---------------------------------------------------------------------------
__global__ __launch_bounds__(256) void gates_ru(
    const float* __restrict__ xfeat, const float* __restrict__ rk,
    const float* __restrict__ rbias, const float* __restrict__ uk,
    const float* __restrict__ ubias, const float* __restrict__ inputs,
    const float* __restrict__ h_prev, float* __restrict__ u_buf,
    __hip_bfloat16* __restrict__ x0tc) {
  const int row0 = blockIdx.x * 32;
  const int b = row0 >> 10, n0 = row0 & 1023;
  const int t = threadIdx.x;
  __shared__ float xm[32][132];
  __shared__ float x0s[32][66];

  {
    const float4* xsrc = reinterpret_cast<const float4*>(xfeat + (size_t)row0 * kXR);
    float4* xdst = reinterpret_cast<float4*>(&xm[0][0]);
#pragma unroll
    for (int r2 = 0; r2 < 5; ++r2) {
      int fl = t + (r2 << 8);
      if (fl < 1056) xdst[fl] = xsrc[fl];
    }
  }
#pragma unroll
  for (int r2 = 0; r2 < 8; ++r2) {
    int idx = t + (r2 << 8);
    int rw = idx >> 6, u = idx & 63;
    x0s[rw][2 + u] = h_prev[(size_t)(row0 + rw) * kU + u];
  }
  if (t < 64) x0s[t >> 1][t & 1] = inputs[(size_t)row0 * 2 + t];
  __syncthreads();

  const int cu = t & 15;
  const int rw = (t >> 4) * 2;
  float ar[2][4] = {{0.f,0.f,0.f,0.f},{0.f,0.f,0.f,0.f}};
  float au[2][4] = {{0.f,0.f,0.f,0.f},{0.f,0.f,0.f,0.f}};

#pragma unroll 4
  for (int f = 0; f < 66; ++f) {
    float4 vr = *reinterpret_cast<const float4*>(rk + (size_t)(f * 3) * kU + cu * 4);
    float4 vu = *reinterpret_cast<const float4*>(uk + (size_t)(f * 3) * kU + cu * 4);
    float a0 = x0s[rw][f], a1 = x0s[rw + 1][f];
    ar[0][0] += a0 * vr.x; ar[0][1] += a0 * vr.y; ar[0][2] += a0 * vr.z; ar[0][3] += a0 * vr.w;
    ar[1][0] += a1 * vr.x; ar[1][1] += a1 * vr.y; ar[1][2] += a1 * vr.z; ar[1][3] += a1 * vr.w;
    au[0][0] += a0 * vu.x; au[0][1] += a0 * vu.y; au[0][2] += a0 * vu.z; au[0][3] += a0 * vu.w;
    au[1][0] += a1 * vu.x; au[1][1] += a1 * vu.y; au[1][2] += a1 * vu.z; au[1][3] += a1 * vu.w;
  }
#pragma unroll
  for (int m = 1; m <= 2; ++m) {
#pragma unroll 4
    for (int f = 0; f < 66; ++f) {
      float4 vr = *reinterpret_cast<const float4*>(rk + (size_t)(f * 3 + m) * kU + cu * 4);
      float4 vu = *reinterpret_cast<const float4*>(uk + (size_t)(f * 3 + m) * kU + cu * 4);
      float a0 = xm[rw][(m - 1) * 66 + f], a1 = xm[rw + 1][(m - 1) * 66 + f];
      ar[0][0] += a0 * vr.x; ar[0][1] += a0 * vr.y; ar[0][2] += a0 * vr.z; ar[0][3] += a0 * vr.w;
      ar[1][0] += a1 * vr.x; ar[1][1] += a1 * vr.y; ar[1][2] += a1 * vr.z; ar[1][3] += a1 * vr.w;
      au[0][0] += a0 * vu.x; au[0][1] += a0 * vu.y; au[0][2] += a0 * vu.z; au[0][3] += a0 * vu.w;
      au[1][0] += a1 * vu.x; au[1][1] += a1 * vu.y; au[1][2] += a1 * vu.z; au[1][3] += a1 * vu.w;
    }
  }

#pragma unroll
  for (int rr = 0; rr < 2; ++rr) {
    int grow = row0 + rw + rr;
    int n = n0 + rw + rr;
#pragma unroll
    for (int j = 0; j < 4; ++j) {
      int u = cu * 4 + j;
      float rv = 1.f / (1.f + __expf(-(ar[rr][j] + rbias[u])));
      float uv = 1.f / (1.f + __expf(-(au[rr][j] + ubias[u])));
      u_buf[(size_t)grow * kU + u] = uv;
      float rh = rv * h_prev[(size_t)grow * kU + u];
      x0tc[((size_t)b * kFP + 2 + u) * kN + n] = __float2bfloat16(rh);
    }
  }
}

// ---------------------------------------------------------------------------
// K5: c gate + GRU update.
// ---------------------------------------------------------------------------
__global__ __launch_bounds__(256) void gate_c_final(
    const float* __restrict__ xfeat, const float* __restrict__ ck,
    const float* __restrict__ cbias, const float* __restrict__ inputs,
    const __hip_bfloat16* __restrict__ x0tc, const float* __restrict__ h_prev,
    const float* __restrict__ u_buf, float* __restrict__ out) {
  const int row0 = blockIdx.x * 32;
  const int b = row0 >> 10, n0 = row0 & 1023;
  const int t = threadIdx.x;
  __shared__ float xm[32][132];
  __shared__ float x0c[32][66];

  {
    const float4* xsrc = reinterpret_cast<const float4*>(xfeat + (size_t)row0 * kXR);
    float4* xdst = reinterpret_cast<float4*>(&xm[0][0]);
#pragma unroll
    for (int r2 = 0; r2 < 5; ++r2) {
      int fl = t + (r2 << 8);
      if (fl < 1056) xdst[fl] = xsrc[fl];
    }
  }
#pragma unroll
  for (int r2 = 0; r2 < 8; ++r2) {
    int idx = t + (r2 << 8);
    int u = idx >> 5, nn = idx & 31;
    x0c[nn][2 + u] =
        __bfloat162float(x0tc[((size_t)b * kFP + 2 + u) * kN + n0 + nn]);
  }
  if (t < 64) x0c[t >> 1][t & 1] = inputs[(size_t)row0 * 2 + t];
  __syncthreads();

  const int cu = t & 15;
  const int rw = (t >> 4) * 2;
  float ac[2][4] = {{0.f,0.f,0.f,0.f},{0.f,0.f,0.f,0.f}};

#pragma unroll 4
  for (int f = 0; f < 66; ++f) {
    float4 vc = *reinterpret_cast<const float4*>(ck + (size_t)(f * 3) * kU + cu * 4);
    float a0 = x0c[rw][f], a1 = x0c[rw + 1][f];
    ac[0][0] += a0 * vc.x; ac[0][1] += a0 * vc.y; ac[0][2] += a0 * vc.z; ac[0][3] += a0 * vc.w;
    ac[1][0] += a1 * vc.x; ac[1][1] += a1 * vc.y; ac[1][2] += a1 * vc.z; ac[1][3] += a1 * vc.w;
  }
#pragma unroll
  for (int m = 1; m <= 2; ++m) {
#pragma unroll 4
    for (int f = 0; f < 66; ++f) {
      float4 vc = *reinterpret_cast<const float4*>(ck + (size_t)(f * 3 + m) * kU + cu * 4);
      float a0 = xm[rw][(m - 1) * 66 + f], a1 = xm[rw + 1][(m - 1) * 66 + f];
      ac[0][0] += a0 * vc.x; ac[0][1] += a0 * vc.y; ac[0][2] += a0 * vc.z; ac[0][3] += a0 * vc.w;
      ac[1][0] += a1 * vc.x; ac[1][1] += a1 * vc.y; ac[1][2] += a1 * vc.z; ac[1][3] += a1 * vc.w;
    }
  }

#pragma unroll
  for (int rr = 0; rr < 2; ++rr) {
    int grow = row0 + rw + rr;
#pragma unroll
    for (int j = 0; j < 4; ++j) {
      int u = cu * 4 + j;
      float cv = tanhf(ac[rr][j] + cbias[u]);
      float uv = u_buf[(size_t)grow * kU + u];
      float hp = h_prev[(size_t)grow * kU + u];
      out[(size_t)grow * kU + u] = uv * hp + (1.f - uv) * cv;
    }
  }
}

}  // namespace

extern "C" void kernel_launch(void* const* d_in, const int* in_sizes, int n_in,
                              void* d_out, int out_size, void* d_ws, size_t ws_size,
                              hipStream_t stream) {
  const float* inputs = (const float*)d_in[0];
  const float* sup    = (const float*)d_in[1];
  const float* h_prev = (const float*)d_in[2];
  const float* rk     = (const float*)d_in[3];
  const float* rbias  = (const float*)d_in[4];
  const float* uk     = (const float*)d_in[5];
  const float* ubias  = (const float*)d_in[6];
  const float* ck     = (const float*)d_in[7];
  const float* cbias  = (const float*)d_in[8];
  float* out = (float*)d_out;

  char* ws = (char*)d_ws;
  __hip_bfloat16* x0t   = (__hip_bfloat16*)(ws);                    //  5,242,880 B
  __hip_bfloat16* x0tc  = (__hip_bfloat16*)(ws + 5242880);          //  5,242,880 B
  float*          xfeat = (float*)(ws + 10485760);                  // 17,301,504 B
  float*          u_buf = (float*)(ws + 27787264);                  //  8,388,608 B

  hipLaunchKernelGGL(build_x0t, dim3(512), dim3(256), 0, stream,
                     inputs, h_prev, x0t, x0tc);
  hipLaunchKernelGGL(einsum_diff, dim3(1024), dim3(256), 0, stream,
                     sup, x0t, xfeat);
  hipLaunchKernelGGL(gates_ru, dim3(1024), dim3(256), 0, stream,
                     xfeat, rk, rbias, uk, ubias, inputs, h_prev, u_buf, x0tc);
  hipLaunchKernelGGL(einsum_diff, dim3(1024), dim3(256), 0, stream,
                     sup, x0tc, xfeat);
  hipLaunchKernelGGL(gate_c_final, dim3(1024), dim3(256), 0, stream,
                     xfeat, ck, cbias, inputs, x0tc, h_prev, u_buf, out);
}

// Round 4
// 232.649 us; speedup vs baseline: 1.6662x; 1.0901x over previous
//
#include <hip/hip_runtime.h>
#include <hip/hip_bf16.h>

namespace {

constexpr int kN  = 1024;
constexpr int kU  = 64;
constexpr int kFP = 80;   // padded feature dim (5 tiles of 16)
constexpr int kXR = 132;  // xfeat row = 2 supports * 66 features

typedef __attribute__((ext_vector_type(4))) float f32x4;
typedef __attribute__((ext_vector_type(8))) short sv8;
typedef unsigned int u32;
typedef unsigned short u16;

__device__ __forceinline__ u32 pack_bf2(float a, float b) {
  __hip_bfloat16 ha = __float2bfloat16(a);
  __hip_bfloat16 hb = __float2bfloat16(b);
  u16 ua = *reinterpret_cast<u16*>(&ha);
  u16 ub = *reinterpret_cast<u16*>(&hb);
  return (u32)ua | ((u32)ub << 16);
}

__device__ __forceinline__ u16 bf16bits(float a) {
  __hip_bfloat16 h = __float2bfloat16(a);
  return *reinterpret_cast<u16*>(&h);
}

__device__ __forceinline__ float bflo(u32 v) {
  u32 x = v << 16;
  return *reinterpret_cast<float*>(&x);
}
__device__ __forceinline__ float bfhi(u32 v) {
  u32 x = v & 0xffff0000u;
  return *reinterpret_cast<float*>(&x);
}

__device__ __forceinline__ void gl16(const void* g, void* l) {
  __builtin_amdgcn_global_load_lds(
      (const __attribute__((address_space(1))) u32*)g,
      (__attribute__((address_space(3))) u32*)l, 16, 0, 0);
}

// ---------------------------------------------------------------------------
// K1: build x0^T bf16 (B, 80, 1024).
// ---------------------------------------------------------------------------
__global__ __launch_bounds__(256) void build_x0t(
    const float* __restrict__ inputs, const float* __restrict__ h_prev,
    __hip_bfloat16* __restrict__ x0t, __hip_bfloat16* __restrict__ x0tc) {
  const int bx = blockIdx.x;
  const int b  = bx >> 4;
  const int n0 = (bx & 15) * 64;
  const int t  = threadIdx.x;

  __shared__ float hp[64][65];

  const float* hpg = h_prev + (size_t)b * kN * kU + (size_t)n0 * kU;
#pragma unroll
  for (int r = 0; r < 16; ++r) {
    int idx = t + (r << 8);
    hp[idx >> 6][idx & 63] = hpg[idx];
  }
  __syncthreads();

  {
    int u = t >> 2, g = t & 3;
    __hip_bfloat16* dst = x0t + ((size_t)b * kFP + 2 + u) * kN + n0 + g * 16;
#pragma unroll
    for (int k = 0; k < 16; ++k) dst[k] = __float2bfloat16(hp[g * 16 + k][u]);
  }

  if (t < 128) {
    int d = t & 1, nn = t >> 1;
    float v = inputs[((size_t)b * kN + n0 + nn) * 2 + d];
    __hip_bfloat16 bv = __float2bfloat16(v);
    x0t [((size_t)b * kFP + d) * kN + n0 + nn] = bv;
    x0tc[((size_t)b * kFP + d) * kN + n0 + nn] = bv;
  } else {
    int i2 = t - 128;
    __hip_bfloat16 z = __float2bfloat16(0.0f);
#pragma unroll
    for (int r = 0; r < 7; ++r) {
      int idx = i2 + r * 128;
      int row = 66 + (idx >> 6), nn = idx & 63;
      x0t [((size_t)b * kFP + row) * kN + n0 + nn] = z;
      x0tc[((size_t)b * kFP + row) * kN + n0 + nn] = z;
    }
  }
}

// ---------------------------------------------------------------------------
// K2/K4: graph-diffusion einsum, bf16 MFMA.
// 64-row i-tile, 512 threads, 8 waves = s(2) x ih(4). 512 blocks, 2/CU.
// A: 1 contiguous 64B unit/thread -> 2x ds_write_b128 (XOR bank-swizzled).
// X: global_load_lds DMA (L2-resident via XCD-chunked block swizzle).
// 2-phase pipeline: issue(t+1) -> compute(t) -> vmcnt(0) -> pack -> barrier.
// Output xfeat bf16 [row][132], coalesced via LDS transpose.
// ---------------------------------------------------------------------------
__global__ __launch_bounds__(512, 4) void einsum_diff(
    const float* __restrict__ sup, const __hip_bfloat16* __restrict__ x0t,
    u16* __restrict__ xfeat) {
  const int bx = blockIdx.x;
  const int wk = (bx & 7) * 64 + (bx >> 3);  // XCD-chunked (512 = 8*64)
  const int b  = wk >> 4;
  const int i0 = (wk & 15) << 6;
  const int t    = threadIdx.x;
  const int lane = t & 63;
  const int w    = t >> 6;       // 0..7
  const int q    = lane >> 4;
  const int lm   = lane & 15;
  const int s    = w & 1;
  const int ih   = w >> 1;       // 0..3

  // Af region per (buf,s): ks*4096 + ihh*1024 + swizzled slot*16  (8 KB)
  __shared__ u16 Af[2][2][2][4][64][8];  // 32 KB
  __shared__ u16 Xf[2][10][64][8];       // 20 KB

  f32x4 acc[5];
#pragma unroll
  for (int n = 0; n < 5; ++n) acc[n] = (f32x4){0.f, 0.f, 0.f, 0.f};

  const float* sbase = sup + ((size_t)b * kN + i0) * (kN * 2);
  const u16* xg = reinterpret_cast<const u16*>(x0t) + (size_t)b * kFP * kN;

  // ---- A staging unit: thread -> (row ii, j8-group jb) ----
  const int ii = t >> 3, jb = t & 7;
  const float* aSrc = sbase + (size_t)ii * (kN * 2) + jb * 16;
  const int ksA = jb >> 2, q2 = jb & 3;
  const int ihhA = ii >> 4, lm2 = ii & 15;
  const int aOff = ksA * 4096 + ihhA * 1024 +
                   ((((q2 * 16 + lm2) * 16)) ^ (q2 << 4) ^ (ksA << 6));
  char* const afBase = (char*)&Af[0][0][0][0][0][0];

  // ---- X DMA sources (seg = ks*5+n) ----
  const int seg1 = w;
  const int seg2 = w + 8;  // valid for w<2
  const u16* xs1;
  const u16* xs2 = nullptr;
  {
    int k1 = seg1 / 5, n1 = seg1 % 5;
    xs1 = xg + (size_t)(n1 * 16 + lm) * kN + k1 * 32 + q * 8;
    if (w < 2) {
      int k2 = seg2 / 5, n2 = seg2 % 5;
      xs2 = xg + (size_t)(n2 * 16 + lm) * kN + k2 * 32 + q * 8;
    }
  }

  float4 R[4];

  auto dmaX = [&](int nb, int T) {
    int jo = T * 64;
    gl16(xs1 + jo, &Xf[nb][seg1][0][0]);
    if (w < 2) gl16(xs2 + jo, &Xf[nb][seg2][0][0]);
  };

  auto loadA = [&](int T) {
    const float* p = aSrc + T * 128;
    R[0] = *reinterpret_cast<const float4*>(p);
    R[1] = *reinterpret_cast<const float4*>(p + 4);
    R[2] = *reinterpret_cast<const float4*>(p + 8);
    R[3] = *reinterpret_cast<const float4*>(p + 12);
  };

  auto packWrite = [&](int nb) {
    u32 p0[4], p1[4];
#pragma unroll
    for (int r = 0; r < 4; ++r) {
      p0[r] = pack_bf2(R[r].x, R[r].z);
      p1[r] = pack_bf2(R[r].y, R[r].w);
    }
    char* base = afBase + nb * 16384 + aOff;
    *reinterpret_cast<uint4*>(base)        = *reinterpret_cast<uint4*>(p0);
    *reinterpret_cast<uint4*>(base + 8192) = *reinterpret_cast<uint4*>(p1);
  };

  auto compute = [&](int cb_) {
#pragma unroll
    for (int ks = 0; ks < 2; ++ks) {
      const char* ab = afBase + cb_ * 16384 + s * 8192 + ks * 4096 + ih * 1024;
      sv8 a = *reinterpret_cast<const sv8*>(
          ab + ((((q * 16 + lm) * 16)) ^ (q << 4) ^ (ks << 6)));
#pragma unroll
      for (int n = 0; n < 5; ++n) {
        sv8 xb = *reinterpret_cast<const sv8*>(&Xf[cb_][ks * 5 + n][lane][0]);
        acc[n] = __builtin_amdgcn_mfma_f32_16x16x32_bf16(a, xb, acc[n], 0, 0, 0);
      }
    }
  };

  // ---- prologue: stage tile 0 ----
  dmaX(0, 0);
  loadA(0);
  asm volatile("s_waitcnt vmcnt(0)" ::: "memory");
  packWrite(0);
  asm volatile("s_waitcnt lgkmcnt(0)" ::: "memory");
  __builtin_amdgcn_s_barrier();
  __builtin_amdgcn_sched_barrier(0);

#pragma unroll 1
  for (int T = 0; T < 15; ++T) {
    const int nb = (T + 1) & 1;
    dmaX(nb, T + 1);
    loadA(T + 1);
    compute(T & 1);
    asm volatile("s_waitcnt vmcnt(0)" ::: "memory");
    packWrite(nb);
    asm volatile("s_waitcnt lgkmcnt(0)" ::: "memory");
    __builtin_amdgcn_s_barrier();
    __builtin_amdgcn_sched_barrier(0);
  }
  compute(1);  // tile 15
  __syncthreads();  // before LDS reuse

  // ---- epilogue: acc -> LDS bf16 [64][136] -> coalesced global ----
  u16* ep = (u16*)afBase;
#pragma unroll
  for (int n = 0; n < 5; ++n) {
    int f = n * 16 + lm;
    if (f < 66) {
#pragma unroll
      for (int r = 0; r < 4; ++r) {
        int row = ih * 16 + q * 4 + r;
        ep[row * 136 + s * 66 + f] = bf16bits(acc[n][r]);
      }
    }
  }
  __syncthreads();
  const u32* ep32 = (const u32*)afBase;  // [64][68]
  u32* og = reinterpret_cast<u32*>(xfeat) + ((size_t)b * kN + i0) * 66;
#pragma unroll 1
  for (int g = t; g < 4224; g += 512) {
    int row = g / 66, c = g - row * 66;
    og[g] = ep32[row * 68 + c];
  }
}

// ---------------------------------------------------------------------------
// K3: r/u gates (xfeat bf16).
// ---------------------------------------------------------------------------
__global__ __launch_bounds__(256) void gates_ru(
    const u16* __restrict__ xfeat, const float* __restrict__ rk,
    const float* __restrict__ rbias, const float* __restrict__ uk,
    const float* __restrict__ ubias, const float* __restrict__ inputs,
    const float* __restrict__ h_prev, float* __restrict__ u_buf,
    __hip_bfloat16* __restrict__ x0tc) {
  const int row0 = blockIdx.x * 32;
  const int b = row0 >> 10, n0 = row0 & 1023;
  const int t = threadIdx.x;
  __shared__ float xm[32][134];
  __shared__ float x0s[32][66];

  {
    const u32* xsrc = reinterpret_cast<const u32*>(xfeat) + (size_t)row0 * 66;
#pragma unroll 1
    for (int g = t; g < 2112; g += 256) {
      int row = g / 66, c = g - row * 66;
      u32 v = xsrc[g];
      xm[row][c * 2]     = bflo(v);
      xm[row][c * 2 + 1] = bfhi(v);
    }
  }
#pragma unroll
  for (int r2 = 0; r2 < 8; ++r2) {
    int idx = t + (r2 << 8);
    int rw = idx >> 6, u = idx & 63;
    x0s[rw][2 + u] = h_prev[(size_t)(row0 + rw) * kU + u];
  }
  if (t < 64) x0s[t >> 1][t & 1] = inputs[(size_t)row0 * 2 + t];
  __syncthreads();

  const int cu = t & 15;
  const int rw = (t >> 4) * 2;
  float ar[2][4] = {{0.f,0.f,0.f,0.f},{0.f,0.f,0.f,0.f}};
  float au[2][4] = {{0.f,0.f,0.f,0.f},{0.f,0.f,0.f,0.f}};

#pragma unroll 4
  for (int f = 0; f < 66; ++f) {  // m = 0
    float4 vr = *reinterpret_cast<const float4*>(rk + (size_t)(f * 3) * kU + cu * 4);
    float4 vu = *reinterpret_cast<const float4*>(uk + (size_t)(f * 3) * kU + cu * 4);
    float a0 = x0s[rw][f], a1 = x0s[rw + 1][f];
    ar[0][0] += a0 * vr.x; ar[0][1] += a0 * vr.y; ar[0][2] += a0 * vr.z; ar[0][3] += a0 * vr.w;
    ar[1][0] += a1 * vr.x; ar[1][1] += a1 * vr.y; ar[1][2] += a1 * vr.z; ar[1][3] += a1 * vr.w;
    au[0][0] += a0 * vu.x; au[0][1] += a0 * vu.y; au[0][2] += a0 * vu.z; au[0][3] += a0 * vu.w;
    au[1][0] += a1 * vu.x; au[1][1] += a1 * vu.y; au[1][2] += a1 * vu.z; au[1][3] += a1 * vu.w;
  }
#pragma unroll
  for (int m = 1; m <= 2; ++m) {
#pragma unroll 4
    for (int f = 0; f < 66; ++f) {
      float4 vr = *reinterpret_cast<const float4*>(rk + (size_t)(f * 3 + m) * kU + cu * 4);
      float4 vu = *reinterpret_cast<const float4*>(uk + (size_t)(f * 3 + m) * kU + cu * 4);
      float a0 = xm[rw][(m - 1) * 66 + f], a1 = xm[rw + 1][(m - 1) * 66 + f];
      ar[0][0] += a0 * vr.x; ar[0][1] += a0 * vr.y; ar[0][2] += a0 * vr.z; ar[0][3] += a0 * vr.w;
      ar[1][0] += a1 * vr.x; ar[1][1] += a1 * vr.y; ar[1][2] += a1 * vr.z; ar[1][3] += a1 * vr.w;
      au[0][0] += a0 * vu.x; au[0][1] += a0 * vu.y; au[0][2] += a0 * vu.z; au[0][3] += a0 * vu.w;
      au[1][0] += a1 * vu.x; au[1][1] += a1 * vu.y; au[1][2] += a1 * vu.z; au[1][3] += a1 * vu.w;
    }
  }

#pragma unroll
  for (int rr = 0; rr < 2; ++rr) {
    int grow = row0 + rw + rr;
    int n = n0 + rw + rr;
#pragma unroll
    for (int j = 0; j < 4; ++j) {
      int u = cu * 4 + j;
      float rv = 1.f / (1.f + __expf(-(ar[rr][j] + rbias[u])));
      float uv = 1.f / (1.f + __expf(-(au[rr][j] + ubias[u])));
      u_buf[(size_t)grow * kU + u] = uv;
      float rh = rv * h_prev[(size_t)grow * kU + u];
      x0tc[((size_t)b * kFP + 2 + u) * kN + n] = __float2bfloat16(rh);
    }
  }
}

// ---------------------------------------------------------------------------
// K5: c gate + GRU update (xfeat bf16).
// ---------------------------------------------------------------------------
__global__ __launch_bounds__(256) void gate_c_final(
    const u16* __restrict__ xfeat, const float* __restrict__ ck,
    const float* __restrict__ cbias, const float* __restrict__ inputs,
    const __hip_bfloat16* __restrict__ x0tc, const float* __restrict__ h_prev,
    const float* __restrict__ u_buf, float* __restrict__ out) {
  const int row0 = blockIdx.x * 32;
  const int b = row0 >> 10, n0 = row0 & 1023;
  const int t = threadIdx.x;
  __shared__ float xm[32][134];
  __shared__ float x0c[32][66];

  {
    const u32* xsrc = reinterpret_cast<const u32*>(xfeat) + (size_t)row0 * 66;
#pragma unroll 1
    for (int g = t; g < 2112; g += 256) {
      int row = g / 66, c = g - row * 66;
      u32 v = xsrc[g];
      xm[row][c * 2]     = bflo(v);
      xm[row][c * 2 + 1] = bfhi(v);
    }
  }
#pragma unroll
  for (int r2 = 0; r2 < 8; ++r2) {
    int idx = t + (r2 << 8);
    int u = idx >> 5, nn = idx & 31;
    x0c[nn][2 + u] =
        __bfloat162float(x0tc[((size_t)b * kFP + 2 + u) * kN + n0 + nn]);
  }
  if (t < 64) x0c[t >> 1][t & 1] = inputs[(size_t)row0 * 2 + t];
  __syncthreads();

  const int cu = t & 15;
  const int rw = (t >> 4) * 2;
  float ac[2][4] = {{0.f,0.f,0.f,0.f},{0.f,0.f,0.f,0.f}};

#pragma unroll 4
  for (int f = 0; f < 66; ++f) {  // m = 0
    float4 vc = *reinterpret_cast<const float4*>(ck + (size_t)(f * 3) * kU + cu * 4);
    float a0 = x0c[rw][f], a1 = x0c[rw + 1][f];
    ac[0][0] += a0 * vc.x; ac[0][1] += a0 * vc.y; ac[0][2] += a0 * vc.z; ac[0][3] += a0 * vc.w;
    ac[1][0] += a1 * vc.x; ac[1][1] += a1 * vc.y; ac[1][2] += a1 * vc.z; ac[1][3] += a1 * vc.w;
  }
#pragma unroll
  for (int m = 1; m <= 2; ++m) {
#pragma unroll 4
    for (int f = 0; f < 66; ++f) {
      float4 vc = *reinterpret_cast<const float4*>(ck + (size_t)(f * 3 + m) * kU + cu * 4);
      float a0 = xm[rw][(m - 1) * 66 + f], a1 = xm[rw + 1][(m - 1) * 66 + f];
      ac[0][0] += a0 * vc.x; ac[0][1] += a0 * vc.y; ac[0][2] += a0 * vc.z; ac[0][3] += a0 * vc.w;
      ac[1][0] += a1 * vc.x; ac[1][1] += a1 * vc.y; ac[1][2] += a1 * vc.z; ac[1][3] += a1 * vc.w;
    }
  }

#pragma unroll
  for (int rr = 0; rr < 2; ++rr) {
    int grow = row0 + rw + rr;
#pragma unroll
    for (int j = 0; j < 4; ++j) {
      int u = cu * 4 + j;
      float cv = tanhf(ac[rr][j] + cbias[u]);
      float uv = u_buf[(size_t)grow * kU + u];
      float hp = h_prev[(size_t)grow * kU + u];
      out[(size_t)grow * kU + u] = uv * hp + (1.f - uv) * cv;
    }
  }
}

}  // namespace

extern "C" void kernel_launch(void* const* d_in, const int* in_sizes, int n_in,
                              void* d_out, int out_size, void* d_ws, size_t ws_size,
                              hipStream_t stream) {
  const float* inputs = (const float*)d_in[0];
  const float* sup    = (const float*)d_in[1];
  const float* h_prev = (const float*)d_in[2];
  const float* rk     = (const float*)d_in[3];
  const float* rbias  = (const float*)d_in[4];
  const float* uk     = (const float*)d_in[5];
  const float* ubias  = (const float*)d_in[6];
  const float* ck     = (const float*)d_in[7];
  const float* cbias  = (const float*)d_in[8];
  float* out = (float*)d_out;

  char* ws = (char*)d_ws;
  __hip_bfloat16* x0t   = (__hip_bfloat16*)(ws);                    //  5,242,880 B
  __hip_bfloat16* x0tc  = (__hip_bfloat16*)(ws + 5242880);          //  5,242,880 B
  u16*            xfeat = (u16*)(ws + 10485760);                    //  8,650,752 B
  float*          u_buf = (float*)(ws + 19136512);                  //  8,388,608 B

  hipLaunchKernelGGL(build_x0t, dim3(512), dim3(256), 0, stream,
                     inputs, h_prev, x0t, x0tc);
  hipLaunchKernelGGL(einsum_diff, dim3(512), dim3(512), 0, stream,
                     sup, x0t, xfeat);
  hipLaunchKernelGGL(gates_ru, dim3(1024), dim3(256), 0, stream,
                     xfeat, rk, rbias, uk, ubias, inputs, h_prev, u_buf, x0tc);
  hipLaunchKernelGGL(einsum_diff, dim3(512), dim3(512), 0, stream,
                     sup, x0tc, xfeat);
  hipLaunchKernelGGL(gate_c_final, dim3(1024), dim3(256), 0, stream,
                     xfeat, ck, cbias, inputs, x0tc, h_prev, u_buf, out);
}